// Round 5
// baseline (253.693 us; speedup 1.0000x reference)
//
#include <hip/hip_runtime.h>
#include <hip/hip_cooperative_groups.h>
#include <math.h>

namespace cg = cooperative_groups;

// Chamfer distance, B=4, H=W=128, HW=16384, threshold 0.1.
// ws layout:
//   [0,32)    int counts[8]      (memset to 0 each call)
//   [32,64)   float sums[8]      (memset to 0 each call)
//   [256, 256+8*HW*16)   float4 pts[8][HW]   (x, y, |q|^2, pad)
//   [+2MB, +2MB+8*HW*4)  uint  minarr[8][HW] (d^2 bits, atomicMin)

#define B_ 4
#define HW_ 16384
#define THRESH 0.1f
#define BIGF 1e30f
#define EPS_ 1e-12f

#define NBLK 512       // cooperative grid: 2 blocks/CU co-resident (safe margin)
#define NTHR 512       // 8 waves/block -> 16 waves/CU occupancy
#define NCHUNK 32      // to-dimension split
#define RROWS 8        // rows/thread: balances ds_read_b128 (12cyc) vs VALU demand
#define ROWSPT (NTHR * RROWS)   // 4096 rows per tile
#define MAXCHUNK 512   // ceil(HW/NCHUNK)

__device__ __forceinline__ int ld_agent_i(const int* p) {
    return __hip_atomic_load(p, __ATOMIC_RELAXED, __HIP_MEMORY_SCOPE_AGENT);
}
__device__ __forceinline__ unsigned int ld_agent_u(const unsigned int* p) {
    return __hip_atomic_load(p, __ATOMIC_RELAXED, __HIP_MEMORY_SCOPE_AGENT);
}
__device__ __forceinline__ float ld_agent_f(const float* p) {
    return __hip_atomic_load(p, __ATOMIC_RELAXED, __HIP_MEMORY_SCOPE_AGENT);
}

__global__ __launch_bounds__(NTHR, 4)   // 4 waves/EU -> 2 blocks/CU, VGPR cap 128
void fused_kernel(const float* __restrict__ in1, const float* __restrict__ in2,
                  int* counts, float* sums, float4* pts,
                  unsigned int* minarr, float* out) {
    cg::grid_group grid = cg::this_grid();
    const int bid = blockIdx.x, tid = threadIdx.x;

    __shared__ float4 buf[MAXCHUNK];

    // ---- P1: relu-threshold compaction + minarr init (blocks 0..255) ----
    if (bid < 256) {
        int g = bid * NTHR + tid;            // [0, 131072) = 2 sets x B*HW
        int s = g >> 16;                     // set 0/1
        int e = g & 65535;                   // element within set
        const float* in = s ? in2 : in1;
        float v = in[e];
        float w = v - THRESH;
        bool active = w > 0.0f;
        int b = e >> 14;
        int i = e & (HW_ - 1);
        int combo = b * 2 + s;
        minarr[combo * HW_ + i] = __float_as_uint(BIGF);
        unsigned long long mask = __ballot(active);
        int lane = tid & 63;
        int pop = __popcll(mask);
        int base = 0;
        if (lane == 0 && pop) base = atomicAdd(&counts[combo], pop);
        base = __shfl(base, 0);
        if (active) {
            int off = __popcll(mask & ((1ull << lane) - 1ull));
            float qx = (float)(i >> 7) * w;
            float qy = (float)(i & 127) * w;
            pts[combo * HW_ + base + off] = make_float4(qx, qy, qx * qx + qy * qy, 0.0f);
        }
    }
    grid.sync();

    // ---- P2: dist. bid -> (combo 8, rowtile 2, chunk 32). Stage to-chunk in
    // LDS once; each thread min-reduces RROWS rows (2 FMA + 1 min per pair,
    // dot form). Cross-chunk combine via uint atomicMin on d^2 bits (>=0). ----
    {
        int combo   = bid & 7;
        int rowtile = (bid >> 3) & 1;
        int chunk   = bid >> 4;              // 0..31
        int n_from = ld_agent_i(&counts[combo]);
        int n_to   = ld_agent_i(&counts[combo ^ 1]);
        int len   = (n_to + NCHUNK - 1) / NCHUNK;
        int start = chunk * len;
        int end   = min(start + len, n_to);
        int clen  = end - start;
        const float4* __restrict__ to   = pts + (combo ^ 1) * HW_;
        const float4* __restrict__ from = pts + combo * HW_;
        for (int t = tid; t < clen; t += NTHR) buf[t] = to[start + t];
        __syncthreads();
        if (clen > 0) {
            for (int rbase = rowtile * ROWSPT; rbase < n_from; rbase += 2 * ROWSPT) {
                int row[RROWS];
                float n2px[RROWS], n2py[RROWS], p2[RROWS], m[RROWS];
#pragma unroll
                for (int k = 0; k < RROWS; ++k) {
                    row[k] = rbase + tid + k * NTHR;
                    int r = min(row[k], HW_ - 1);        // clamp: poison-safe junk
                    float4 p = from[r];
                    n2px[k] = -2.0f * p.x;
                    n2py[k] = -2.0f * p.y;
                    p2[k]   = p.z;
                    m[k]    = BIGF;
                }
                int j = 0, c2 = clen & ~1;
                for (; j < c2; j += 2) {
                    float4 q0 = buf[j];                  // uniform -> LDS broadcast
                    float4 q1 = buf[j + 1];
#pragma unroll
                    for (int k = 0; k < RROWS; ++k)
                        m[k] = fminf(m[k], fmaf(q0.y, n2py[k], fmaf(q0.x, n2px[k], q0.z)));
#pragma unroll
                    for (int k = 0; k < RROWS; ++k)
                        m[k] = fminf(m[k], fmaf(q1.y, n2py[k], fmaf(q1.x, n2px[k], q1.z)));
                }
                if (j < clen) {
                    float4 q0 = buf[j];
#pragma unroll
                    for (int k = 0; k < RROWS; ++k)
                        m[k] = fminf(m[k], fmaf(q0.y, n2py[k], fmaf(q0.x, n2px[k], q0.z)));
                }
#pragma unroll
                for (int k = 0; k < RROWS; ++k) {
                    if (row[k] < n_from) {
                        float d2 = fmaxf(m[k] + p2[k], 0.0f);   // >=0 -> uint order ok
                        atomicMin(&minarr[combo * HW_ + row[k]], __float_as_uint(d2));
                    }
                }
            }
        }
    }
    grid.sync();

    // ---- P3: sqrt + per-combo sum. bid -> (combo 8, rowblk 64 x 256 rows) ----
    {
        int combo = bid >> 6;
        int rblk  = bid & 63;
        int n_from = ld_agent_i(&counts[combo]);
        float contrib = 0.0f;
        if (tid < 256) {
            int row = rblk * 256 + tid;
            if (row < n_from) {
                unsigned int u = ld_agent_u(&minarr[combo * HW_ + row]);
                contrib = sqrtf(fmaxf(__uint_as_float(u), EPS_));
            }
        }
#pragma unroll
        for (int o = 32; o >= 1; o >>= 1) contrib += __shfl_down(contrib, o);
        __shared__ float wsum[NTHR / 64];
        if ((tid & 63) == 0) wsum[tid >> 6] = contrib;
        __syncthreads();
        if (tid == 0) {
            float t = 0.0f;
#pragma unroll
            for (int w = 0; w < NTHR / 64; ++w) t += wsum[w];
            atomicAdd(&sums[combo], t);
        }
    }
    grid.sync();

    // ---- P4: output ----
    if (bid == 0 && tid < B_) {
        int n0 = ld_agent_i(&counts[tid * 2]);
        int n1 = ld_agent_i(&counts[tid * 2 + 1]);
        float s0 = ld_agent_f(&sums[tid * 2]);
        float s1 = ld_agent_f(&sums[tid * 2 + 1]);
        out[tid] = (n0 > 0 && n1 > 0) ? s0 / (float)n0 + s1 / (float)n1 : 1.0e6f;
    }
}

// ---------------- Fallback path (if cooperative launch unsupported) ----------------

__global__ void compact_kernel(const float* __restrict__ in1,
                               const float* __restrict__ in2,
                               int* __restrict__ counts,
                               float4* __restrict__ pts,
                               unsigned int* __restrict__ minarr) {
    int s = blockIdx.y;
    int g = blockIdx.x * 256 + threadIdx.x;
    const float* in = (s == 0) ? in1 : in2;
    float v = in[g];
    float w = v - THRESH;
    bool active = w > 0.0f;
    int b = g >> 14;
    int i = g & (HW_ - 1);
    int combo = b * 2 + s;
    minarr[(size_t)combo * HW_ + i] = __float_as_uint(BIGF);
    unsigned long long mask = __ballot(active);
    int lane = threadIdx.x & 63;
    int pop = __popcll(mask);
    int base = 0;
    if (lane == 0 && pop > 0) base = atomicAdd(&counts[combo], pop);
    base = __shfl(base, 0);
    if (active) {
        int off = __popcll(mask & ((1ull << lane) - 1ull));
        float qx = (float)(i >> 7) * w;
        float qy = (float)(i & 127) * w;
        pts[(size_t)combo * HW_ + base + off] = make_float4(qx, qy, qx * qx + qy * qy, 0.0f);
    }
}

__global__ __launch_bounds__(NTHR, 4)
void dist_kernel_fb(const int* __restrict__ counts,
                    const float4* __restrict__ pts,
                    unsigned int* __restrict__ minarr) {
    int combo   = blockIdx.x & 7;
    int rowtile = (blockIdx.x >> 3) & 1;
    int chunk   = blockIdx.x >> 4;
    int tid = threadIdx.x;
    int n_from = counts[combo];
    int n_to   = counts[combo ^ 1];
    int len   = (n_to + NCHUNK - 1) / NCHUNK;
    int start = chunk * len;
    int end   = min(start + len, n_to);
    int clen  = end - start;
    const float4* __restrict__ to   = pts + (combo ^ 1) * HW_;
    const float4* __restrict__ from = pts + combo * HW_;
    __shared__ float4 buf[MAXCHUNK];
    for (int t = tid; t < clen; t += NTHR) buf[t] = to[start + t];
    __syncthreads();
    if (clen <= 0) return;
    for (int rbase = rowtile * ROWSPT; rbase < n_from; rbase += 2 * ROWSPT) {
        int row[RROWS];
        float n2px[RROWS], n2py[RROWS], p2[RROWS], m[RROWS];
#pragma unroll
        for (int k = 0; k < RROWS; ++k) {
            row[k] = rbase + tid + k * NTHR;
            int r = min(row[k], HW_ - 1);
            float4 p = from[r];
            n2px[k] = -2.0f * p.x; n2py[k] = -2.0f * p.y; p2[k] = p.z; m[k] = BIGF;
        }
        int j = 0, c2 = clen & ~1;
        for (; j < c2; j += 2) {
            float4 q0 = buf[j], q1 = buf[j + 1];
#pragma unroll
            for (int k = 0; k < RROWS; ++k)
                m[k] = fminf(m[k], fmaf(q0.y, n2py[k], fmaf(q0.x, n2px[k], q0.z)));
#pragma unroll
            for (int k = 0; k < RROWS; ++k)
                m[k] = fminf(m[k], fmaf(q1.y, n2py[k], fmaf(q1.x, n2px[k], q1.z)));
        }
        if (j < clen) {
            float4 q0 = buf[j];
#pragma unroll
            for (int k = 0; k < RROWS; ++k)
                m[k] = fminf(m[k], fmaf(q0.y, n2py[k], fmaf(q0.x, n2px[k], q0.z)));
        }
#pragma unroll
        for (int k = 0; k < RROWS; ++k) {
            if (row[k] < n_from) {
                float d2 = fmaxf(m[k] + p2[k], 0.0f);
                atomicMin(&minarr[(size_t)combo * HW_ + row[k]], __float_as_uint(d2));
            }
        }
    }
}

__global__ void reduce_kernel_fb(const int* __restrict__ counts,
                                 const unsigned int* __restrict__ minarr,
                                 float* __restrict__ sums) {
    int combo = blockIdx.y;
    int n_from = counts[combo];
    if ((int)(blockIdx.x * 256) >= n_from) return;
    int row = blockIdx.x * 256 + threadIdx.x;
    float contrib = 0.0f;
    if (row < n_from) {
        float d2 = __uint_as_float(minarr[(size_t)combo * HW_ + row]);
        contrib = sqrtf(fmaxf(d2, EPS_));
    }
#pragma unroll
    for (int o = 32; o >= 1; o >>= 1) contrib += __shfl_down(contrib, o);
    __shared__ float wsum[4];
    int wid = threadIdx.x >> 6, lane = threadIdx.x & 63;
    if (lane == 0) wsum[wid] = contrib;
    __syncthreads();
    if (threadIdx.x == 0)
        atomicAdd(&sums[combo], wsum[0] + wsum[1] + wsum[2] + wsum[3]);
}

__global__ void final_kernel_fb(const int* __restrict__ counts,
                                const float* __restrict__ sums,
                                float* __restrict__ out) {
    int b = threadIdx.x;
    if (b < B_) {
        int n0 = counts[b * 2], n1 = counts[b * 2 + 1];
        out[b] = (n0 > 0 && n1 > 0)
                 ? sums[b * 2] / (float)n0 + sums[b * 2 + 1] / (float)n1
                 : 1.0e6f;
    }
}

extern "C" void kernel_launch(void* const* d_in, const int* in_sizes, int n_in,
                              void* d_out, int out_size, void* d_ws, size_t ws_size,
                              hipStream_t stream) {
    const float* in1 = (const float*)d_in[0];
    const float* in2 = (const float*)d_in[1];
    float* out = (float*)d_out;
    char* ws = (char*)d_ws;
    int* counts = (int*)ws;
    float* sums = (float*)(ws + 32);
    float4* pts = (float4*)(ws + 256);
    unsigned int* minarr = (unsigned int*)(ws + 256 + (size_t)8 * HW_ * sizeof(float4));

    hipMemsetAsync(ws, 0, 64, stream);   // zero counts[8] + sums[8]

    void* args[] = {(void*)&in1, (void*)&in2, (void*)&counts, (void*)&sums,
                    (void*)&pts, (void*)&minarr, (void*)&out};
    hipError_t err = hipLaunchCooperativeKernel((const void*)fused_kernel,
                                                dim3(NBLK), dim3(NTHR),
                                                args, 0, stream);
    if (err != hipSuccess) {
        // deterministic fallback: multi-kernel path
        hipLaunchKernelGGL(compact_kernel, dim3((B_ * HW_) / 256, 2), dim3(256), 0, stream,
                           in1, in2, counts, pts, minarr);
        hipLaunchKernelGGL(dist_kernel_fb, dim3(NBLK), dim3(NTHR), 0, stream,
                           counts, pts, minarr);
        hipLaunchKernelGGL(reduce_kernel_fb, dim3(HW_ / 256, 8), dim3(256), 0, stream,
                           counts, minarr, sums);
        hipLaunchKernelGGL(final_kernel_fb, dim3(1), dim3(64), 0, stream,
                           counts, sums, out);
    }
}

// Round 9
// 121.149 us; speedup vs baseline: 2.0941x; 2.0941x over previous
//
#include <hip/hip_runtime.h>
#include <math.h>

// Chamfer distance, B=4, H=W=128, HW=16384, threshold 0.1.
// ws layout:
//   [0,32)    int counts[8]      (memset to 0 each call)
//   [256, 256+8*HW*16)   float4 pts[8][HW]   (x, y, |q|^2, pad)
//   [+2MB, +2MB+8*HW*4)  uint  minarr[8][HW] (d^2 bits, atomicMin)

#define B_ 4
#define HW_ 16384
#define THRESH 0.1f
#define BIGF 1e30f
#define EPS_ 1e-12f

#define NTHR 512       // 8 waves/block
#define RROWS 16       // rows/thread: 1 ds_read_b128 amortized over 16 rows
#define NCHUNK 64      // to-split: 64 x 8 combos = 512 blocks = 2/CU, 16 waves/CU
#define MAXCHUNK 256   // ceil(HW/NCHUNK)

// One thread per input element; per-wave aggregated atomic for compaction.
// Stores (gy*w, gx*w, |q|^2, 0); also inits this thread's minarr slot to BIG.
__global__ void compact_kernel(const float* __restrict__ in1,
                               const float* __restrict__ in2,
                               int* __restrict__ counts,
                               float4* __restrict__ pts,
                               unsigned int* __restrict__ minarr) {
    int s = blockIdx.y;                          // which set (0/1)
    int g = blockIdx.x * 256 + threadIdx.x;      // [0, B*HW)
    const float* in = (s == 0) ? in1 : in2;
    float v = in[g];
    float w = v - THRESH;
    bool active = w > 0.0f;
    int b = g >> 14;                             // / HW
    int i = g & (HW_ - 1);
    int combo = b * 2 + s;

    minarr[combo * HW_ + i] = __float_as_uint(BIGF);

    unsigned long long mask = __ballot(active);
    int lane = threadIdx.x & 63;
    int pop = __popcll(mask);
    int base = 0;
    if (lane == 0 && pop > 0) base = atomicAdd(&counts[combo], pop);
    base = __shfl(base, 0);
    if (active) {
        int off = __popcll(mask & ((1ull << lane) - 1ull));
        float qx = (float)(i >> 7) * w;
        float qy = (float)(i & 127) * w;
        pts[combo * HW_ + base + off] = make_float4(qx, qy, qx * qx + qy * qy, 0.0f);
    }
}

// grid (NCHUNK, 8 combos), 512 threads. Stage this block's to-chunk (<=256
// float4 = 4KB) into LDS once; each thread min-reduces RROWS=16 rows against
// it (dot form: 2 FMA + 0.5 min3 per pair). Cross-chunk combine via uint
// atomicMin on d^2 bits (non-negative -> uint order = float order).
__global__ __launch_bounds__(NTHR, 4)   // 4 waves/EU -> 2 blocks/CU, VGPR<=128
void dist_kernel(const int* __restrict__ counts,
                 const float4* __restrict__ pts,
                 unsigned int* __restrict__ minarr) {
    int chunk = blockIdx.x;
    int combo = blockIdx.y;
    int tid = threadIdx.x;
    int n_from = counts[combo];
    int n_to   = counts[combo ^ 1];
    if (n_from <= 0 || n_to <= 0) return;

    int len   = (n_to + NCHUNK - 1) / NCHUNK;
    int start = chunk * len;
    int end   = min(start + len, n_to);
    int clen  = end - start;
    if (clen <= 0) return;                       // block-uniform, before any sync

    const float4* __restrict__ to   = pts + (combo ^ 1) * HW_;
    const float4* __restrict__ from = pts + combo * HW_;

    __shared__ float4 buf[MAXCHUNK];
    for (int t = tid; t < clen; t += NTHR) buf[t] = to[start + t];
    __syncthreads();

    for (int rbase = 0; rbase < n_from; rbase += NTHR * RROWS) {
        int slot[RROWS];
        float n2px[RROWS], n2py[RROWS], p2[RROWS], m[RROWS];
#pragma unroll
        for (int k = 0; k < RROWS; ++k) {
            slot[k] = rbase + tid + k * NTHR;
            int r = min(slot[k], HW_ - 1);       // in-bounds; junk if invalid
            float4 p = from[r];
            n2px[k] = -2.0f * p.x;
            n2py[k] = -2.0f * p.y;
            p2[k]   = p.z;
            m[k]    = BIGF;
        }
        int j = 0, c2 = clen & ~1;
        for (; j < c2; j += 2) {
            float4 q0 = buf[j];                  // uniform addr -> LDS broadcast
            float4 q1 = buf[j + 1];
#pragma unroll
            for (int k = 0; k < RROWS; ++k) {
                float t0 = fmaf(q0.y, n2py[k], fmaf(q0.x, n2px[k], q0.z));
                float t1 = fmaf(q1.y, n2py[k], fmaf(q1.x, n2px[k], q1.z));
                m[k] = fminf(m[k], fminf(t0, t1));   // -> v_min3_f32
            }
        }
        if (j < clen) {
            float4 q0 = buf[j];
#pragma unroll
            for (int k = 0; k < RROWS; ++k)
                m[k] = fminf(m[k], fmaf(q0.y, n2py[k], fmaf(q0.x, n2px[k], q0.z)));
        }
#pragma unroll
        for (int k = 0; k < RROWS; ++k) {
            if (slot[k] < n_from) {
                float d2 = fmaxf(m[k] + p2[k], 0.0f);
                atomicMin(&minarr[combo * HW_ + slot[k]], __float_as_uint(d2));
            }
        }
    }
}

// One block per batch: sum sqrt(min d^2) for both directions, write out[b].
// No cross-block communication -> no sums array, no final kernel.
__global__ void reduce_out_kernel(const int* __restrict__ counts,
                                  const unsigned int* __restrict__ minarr,
                                  float* __restrict__ out) {
    int b = blockIdx.x;
    int tid = threadIdx.x;
    __shared__ float wsum[NTHR / 64];
    __shared__ float csum[2];

    for (int d = 0; d < 2; ++d) {
        int combo = b * 2 + d;
        int n = counts[combo];
        float acc = 0.0f;
        for (int row = tid; row < n; row += NTHR)
            acc += sqrtf(fmaxf(__uint_as_float(minarr[combo * HW_ + row]), EPS_));
#pragma unroll
        for (int o = 32; o >= 1; o >>= 1) acc += __shfl_down(acc, o);
        if ((tid & 63) == 0) wsum[tid >> 6] = acc;
        __syncthreads();
        if (tid == 0) {
            float t = 0.0f;
#pragma unroll
            for (int w = 0; w < NTHR / 64; ++w) t += wsum[w];
            csum[d] = t;
        }
        __syncthreads();
    }
    if (tid == 0) {
        int n0 = counts[b * 2], n1 = counts[b * 2 + 1];
        out[b] = (n0 > 0 && n1 > 0)
                 ? csum[0] / (float)n0 + csum[1] / (float)n1
                 : 1.0e6f;
    }
}

extern "C" void kernel_launch(void* const* d_in, const int* in_sizes, int n_in,
                              void* d_out, int out_size, void* d_ws, size_t ws_size,
                              hipStream_t stream) {
    const float* in1 = (const float*)d_in[0];
    const float* in2 = (const float*)d_in[1];
    float* out = (float*)d_out;
    char* ws = (char*)d_ws;
    int* counts = (int*)ws;
    float4* pts = (float4*)(ws + 256);
    unsigned int* minarr = (unsigned int*)(ws + 256 + (size_t)8 * HW_ * sizeof(float4));

    hipMemsetAsync(ws, 0, 32, stream);   // zero counts[8]

    hipLaunchKernelGGL(compact_kernel, dim3((B_ * HW_) / 256, 2), dim3(256), 0, stream,
                       in1, in2, counts, pts, minarr);
    hipLaunchKernelGGL(dist_kernel, dim3(NCHUNK, 8), dim3(NTHR), 0, stream,
                       counts, pts, minarr);
    hipLaunchKernelGGL(reduce_out_kernel, dim3(B_), dim3(NTHR), 0, stream,
                       counts, minarr, out);
}

// Round 10
// 116.288 us; speedup vs baseline: 2.1816x; 1.0418x over previous
//
#include <hip/hip_runtime.h>
#include <math.h>

// Chamfer distance, B=4, H=W=128, HW=16384, threshold 0.1.
// ws layout:
//   [0,32)    int counts[8]      (memset to 0 each call)
//   [256, 256+8*HW*16)   float4 pts[8][HW]   (x, y, |q|^2, pad)
//   [+2MB, +2MB+8*HW*4)  uint  minarr[8][HW] (d^2 bits, atomicMin)

#define B_ 4
#define HW_ 16384
#define THRESH 0.1f
#define BIGF 1e30f
#define EPS_ 1e-12f

#define NTHR 512       // 8 waves/block
#define RROWS 16       // rows/thread: keeps ds_read_b128 issue under VALU demand
#define NCHUNK 64      // to-split: 64 x 8 combos = 512 blocks = 2/CU, 16 waves/CU
#define MAXCHUNK 256   // ceil(HW/NCHUNK)

// One thread per input element; per-wave aggregated atomic for compaction.
// Stores (gy*w, gx*w, |q|^2, 0); also inits this thread's minarr slot to BIG.
__global__ void compact_kernel(const float* __restrict__ in1,
                               const float* __restrict__ in2,
                               int* __restrict__ counts,
                               float4* __restrict__ pts,
                               unsigned int* __restrict__ minarr) {
    int s = blockIdx.y;                          // which set (0/1)
    int g = blockIdx.x * 256 + threadIdx.x;      // [0, B*HW)
    const float* in = (s == 0) ? in1 : in2;
    float v = in[g];
    float w = v - THRESH;
    bool active = w > 0.0f;
    int b = g >> 14;                             // / HW
    int i = g & (HW_ - 1);
    int combo = b * 2 + s;

    minarr[combo * HW_ + i] = __float_as_uint(BIGF);

    unsigned long long mask = __ballot(active);
    int lane = threadIdx.x & 63;
    int pop = __popcll(mask);
    int base = 0;
    if (lane == 0 && pop > 0) base = atomicAdd(&counts[combo], pop);
    base = __shfl(base, 0);
    if (active) {
        int off = __popcll(mask & ((1ull << lane) - 1ull));
        float qx = (float)(i >> 7) * w;
        float qy = (float)(i & 127) * w;
        pts[combo * HW_ + base + off] = make_float4(qx, qy, qx * qx + qy * qy, 0.0f);
    }
}

// grid (NCHUNK, 8 combos), 512 threads. Stage this block's to-chunk (<=256
// float4 = 4KB) into LDS once; each thread min-reduces RROWS=16 rows against
// it (dot form: 2 FMA + 0.5 min3 per pair, quad-unrolled). Cross-chunk
// combine via uint atomicMin on d^2 bits (>=0 -> uint order = float order).
__global__ __launch_bounds__(NTHR, 4)   // 4 waves/EU -> 2 blocks/CU, VGPR<=128
void dist_kernel(const int* __restrict__ counts,
                 const float4* __restrict__ pts,
                 unsigned int* __restrict__ minarr) {
    int chunk = blockIdx.x;
    int combo = blockIdx.y;
    int tid = threadIdx.x;
    int n_from = counts[combo];
    int n_to   = counts[combo ^ 1];
    if (n_from <= 0 || n_to <= 0) return;

    int len   = (n_to + NCHUNK - 1) / NCHUNK;
    int start = chunk * len;
    int end   = min(start + len, n_to);
    int clen  = end - start;
    if (clen <= 0) return;                       // block-uniform, before any sync

    const float4* __restrict__ to   = pts + (combo ^ 1) * HW_;
    const float4* __restrict__ from = pts + combo * HW_;

    __shared__ float4 buf[MAXCHUNK];
    for (int t = tid; t < clen; t += NTHR) buf[t] = to[start + t];
    __syncthreads();

    for (int rbase = 0; rbase < n_from; rbase += NTHR * RROWS) {
        int slot[RROWS];
        float n2px[RROWS], n2py[RROWS], p2[RROWS], m[RROWS];
#pragma unroll
        for (int k = 0; k < RROWS; ++k) {
            slot[k] = rbase + tid + k * NTHR;
            int r = min(slot[k], HW_ - 1);       // in-bounds; junk if invalid
            float4 p = from[r];                  // coalesced (stride NTHR)
            n2px[k] = -2.0f * p.x;
            n2py[k] = -2.0f * p.y;
            p2[k]   = p.z;
            m[k]    = BIGF;
        }
        int j = 0, c4 = clen & ~3;
        for (; j < c4; j += 4) {                 // quad-unroll: amortize loop ovh
            float4 q0 = buf[j];                  // uniform addr -> LDS broadcast
            float4 q1 = buf[j + 1];
            float4 q2 = buf[j + 2];
            float4 q3 = buf[j + 3];
#pragma unroll
            for (int k = 0; k < RROWS; ++k) {
                float t0 = fmaf(q0.y, n2py[k], fmaf(q0.x, n2px[k], q0.z));
                float t1 = fmaf(q1.y, n2py[k], fmaf(q1.x, n2px[k], q1.z));
                m[k] = fminf(m[k], fminf(t0, t1));   // -> v_min3_f32
                float t2 = fmaf(q2.y, n2py[k], fmaf(q2.x, n2px[k], q2.z));
                float t3 = fmaf(q3.y, n2py[k], fmaf(q3.x, n2px[k], q3.z));
                m[k] = fminf(m[k], fminf(t2, t3));
            }
        }
        for (; j < clen; ++j) {
            float4 q0 = buf[j];
#pragma unroll
            for (int k = 0; k < RROWS; ++k)
                m[k] = fminf(m[k], fmaf(q0.y, n2py[k], fmaf(q0.x, n2px[k], q0.z)));
        }
#pragma unroll
        for (int k = 0; k < RROWS; ++k) {
            if (slot[k] < n_from) {
                float d2 = fmaxf(m[k] + p2[k], 0.0f);
                atomicMin(&minarr[combo * HW_ + slot[k]], __float_as_uint(d2));
            }
        }
    }
}

// One 1024-thread block per batch; both directions reduced concurrently
// (tid<512 -> dir0, tid>=512 -> dir1). No cross-block communication.
__global__ void reduce_out_kernel(const int* __restrict__ counts,
                                  const unsigned int* __restrict__ minarr,
                                  float* __restrict__ out) {
    int b = blockIdx.x;
    int tid = threadIdx.x;
    int d = tid >> 9;                            // 0 or 1
    int t = tid & 511;
    int combo = b * 2 + d;
    int n = counts[combo];

    float acc = 0.0f;
    for (int row = t; row < n; row += 512)
        acc += sqrtf(fmaxf(__uint_as_float(minarr[combo * HW_ + row]), EPS_));
#pragma unroll
    for (int o = 32; o >= 1; o >>= 1) acc += __shfl_down(acc, o);

    __shared__ float wsum[16];                   // waves 0-7 dir0, 8-15 dir1
    if ((tid & 63) == 0) wsum[tid >> 6] = acc;
    __syncthreads();
    if (tid == 0) {
        float s0 = 0.0f, s1 = 0.0f;
#pragma unroll
        for (int w = 0; w < 8; ++w)  s0 += wsum[w];
#pragma unroll
        for (int w = 8; w < 16; ++w) s1 += wsum[w];
        int n0 = counts[b * 2], n1 = counts[b * 2 + 1];
        out[b] = (n0 > 0 && n1 > 0)
                 ? s0 / (float)n0 + s1 / (float)n1
                 : 1.0e6f;
    }
}

extern "C" void kernel_launch(void* const* d_in, const int* in_sizes, int n_in,
                              void* d_out, int out_size, void* d_ws, size_t ws_size,
                              hipStream_t stream) {
    const float* in1 = (const float*)d_in[0];
    const float* in2 = (const float*)d_in[1];
    float* out = (float*)d_out;
    char* ws = (char*)d_ws;
    int* counts = (int*)ws;
    float4* pts = (float4*)(ws + 256);
    unsigned int* minarr = (unsigned int*)(ws + 256 + (size_t)8 * HW_ * sizeof(float4));

    hipMemsetAsync(ws, 0, 32, stream);   // zero counts[8]

    hipLaunchKernelGGL(compact_kernel, dim3((B_ * HW_) / 256, 2), dim3(256), 0, stream,
                       in1, in2, counts, pts, minarr);
    hipLaunchKernelGGL(dist_kernel, dim3(NCHUNK, 8), dim3(NTHR), 0, stream,
                       counts, pts, minarr);
    hipLaunchKernelGGL(reduce_out_kernel, dim3(B_), dim3(1024), 0, stream,
                       counts, minarr, out);
}